// Round 6
// baseline (542.291 us; speedup 1.0000x reference)
//
#include <hip/hip_runtime.h>

#define SEQ 128
#define HID 32

typedef __attribute__((ext_vector_type(8))) short short8;   // 8 bf16 = 4 VGPR
typedef __attribute__((ext_vector_type(4))) float floatx4;  // MFMA acc

// ---------------- GCN prep (unchanged from round-3 verified version) ----------------

__global__ void count_kernel(const int* __restrict__ idx, int E, int* __restrict__ cnt) {
    int e = (blockIdx.x * blockDim.x + threadIdx.x) * 4;
    if (((E & 3) == 0) && e + 3 < E) {
        int4 d = *(const int4*)(idx + E + e);   // 16B aligned: E%4==0, e%4==0
        atomicAdd(&cnt[d.x], 1);
        atomicAdd(&cnt[d.y], 1);
        atomicAdd(&cnt[d.z], 1);
        atomicAdd(&cnt[d.w], 1);
    } else {
        int lim = min(e + 4, E);
        for (int k = e; k < lim; ++k) atomicAdd(&cnt[idx[E + k]], 1);
    }
}

// Fixed-point pack: q = rn(v * 2^21), biased +2^26 per 32b field -> every added term
// positive and < 2^26.2, no cross-field carry up to ~56 adds (max realistic deg ~12).
// ONE u64 atomic per edge; dinv[src] computed inline from the deg gather.
__device__ __forceinline__ unsigned long long pk2(float xx, float yy, float dv) {
    int qx = __float2int_rn(xx * dv * 2097152.0f);
    int qy = __float2int_rn(yy * dv * 2097152.0f);
    return ((unsigned long long)(unsigned)(qx + (1 << 26)) << 32) |
           (unsigned)(qy + (1 << 26));
}

__global__ void scatter_pk_kernel(const int* __restrict__ idx, int E,
                                  const float2* __restrict__ x2,
                                  const int* __restrict__ deg,
                                  unsigned long long* __restrict__ aggP) {
    int e = (blockIdx.x * blockDim.x + threadIdx.x) * 4;
    if (((E & 3) == 0) && e + 3 < E) {
        int4 s = *(const int4*)(idx + e);
        int4 d = *(const int4*)(idx + E + e);
        float2 v0 = x2[s.x];
        float2 v1 = x2[s.y];
        float2 v2 = x2[s.z];
        float2 v3 = x2[s.w];
        float dv0 = rsqrtf((float)deg[s.x] + 1.0f);
        float dv1 = rsqrtf((float)deg[s.y] + 1.0f);
        float dv2 = rsqrtf((float)deg[s.z] + 1.0f);
        float dv3 = rsqrtf((float)deg[s.w] + 1.0f);
        atomicAdd(&aggP[d.x], pk2(v0.x, v0.y, dv0));
        atomicAdd(&aggP[d.y], pk2(v1.x, v1.y, dv1));
        atomicAdd(&aggP[d.z], pk2(v2.x, v2.y, dv2));
        atomicAdd(&aggP[d.w], pk2(v3.x, v3.y, dv3));
    } else {
        int lim = min(e + 4, E);
        for (int k = e; k < lim; ++k) {
            int s = idx[k];
            int d = idx[E + k];
            float2 v = x2[s];
            float dv = rsqrtf((float)deg[s] + 1.0f);
            atomicAdd(&aggP[d], pk2(v.x, v.y, dv));
        }
    }
}

// ---------------- MFMA LSTM: SINGLE WAVE per 16 nodes, zero barriers ----------------
// One wave owns ALL 8 row-tiles (g=gate 0..3, t1=half 0..1). A-row permutation
// u(p,t1) = 8*(p>>2) + 4*t1 + (p&3)  (same verified formula as the 2-wave kernel,
// t1 in place of w). With the HW-verified C-layout (row16 = 4*(lane>>4)+reg) this
// gives lane (n=lane&15, qq=lane>>4) the pre-acts of ALL FOUR gates for units
// 8qq+{0..7} of node n — exactly the k-slice 8qq+j that the SAME lane supplies in
// the next step's B-frag (verified B layout: lane l holds node l&15, k=8*(l>>4)+j).
// => h never leaves the lane. The recurrence is pure registers + MFMA:
//    NO __syncthreads, NO LDS h-exchange, NO shfl, NO xg duplication.
// Per step: 24 h-MFMAs (3 terms x 8 tiles, C-in = aX computed last step) +
// 24 x-MFMAs building aX(t+1) (depend only on ubuf) + lane-local activations.
// ubuf is written and read by the same wave -> compiler's lgkmcnt suffices.

__device__ __forceinline__ float sigm_f(float x) {
    return __builtin_amdgcn_rcpf(1.0f + __expf(-x));
}
__device__ __forceinline__ float tanh_f(float x) {
    return fmaf(__builtin_amdgcn_rcpf(1.0f + __expf(-2.0f * x)), 2.0f, -1.0f);
}
// truncation split: f = hi + lo (~2^-16 rel); 3-term MFMA keeps fp32-like precision
__device__ __forceinline__ void fsplit(float f, short& hi, short& lo) {
    unsigned u = __float_as_uint(f);
    hi = (short)(u >> 16);
    float r = f - __uint_as_float(u & 0xFFFF0000u);
    lo = (short)(__float_as_uint(r) >> 16);
}

__global__ __launch_bounds__(64, 1) void lstm_sw_kernel(
    const float2* __restrict__ x2,
    const unsigned long long* __restrict__ aggP, const int* __restrict__ deg,
    int N,
    const float* __restrict__ gcn_W, const float* __restrict__ gcn_b,
    const float* __restrict__ w_ih, const float* __restrict__ w_hh,
    const float* __restrict__ b_ih, const float* __restrict__ b_hh,
    const float* __restrict__ fc_W, const float* __restrict__ fc_b,
    float* __restrict__ out) {
    __shared__ float2 ubuf[16][SEQ + 1];   // 16.5 KB; col 128 = zero pad (t=127 prefetch)

    const int lane = threadIdx.x;          // 0..63, single wave
    const int n = lane & 15;               // node within block
    const int qq = lane >> 4;              // k-slice / unit-group selector
    const int base = blockIdx.x * 16;

    // ---- Phase A: stage u[node][t] = dv*(agg + x*dv) into LDS (coalesced) ----
    {
        const float2* xb = x2 + (size_t)base * SEQ;
        const unsigned long long* apb = aggP + (size_t)base * SEQ;
        const int* dgb = deg + (size_t)base * SEQ;
        const int lim = min(16 * SEQ, (N - base) * SEQ);
        #pragma unroll 4
        for (int i = lane; i < 16 * SEQ; i += 64) {
            float2 v = make_float2(0.f, 0.f);
            if (i < lim) {
                int dg = dgb[i];
                float dv = rsqrtf((float)dg + 1.0f);
                float2 xx = xb[i];
                unsigned long long pk = apb[i];
                unsigned bias = (unsigned)dg * 67108864u;  // deg * 2^26
                float ax = (float)((int)((unsigned)(pk >> 32) - bias)) * (1.0f / 2097152.0f);
                float ay = (float)((int)((unsigned)pk - bias)) * (1.0f / 2097152.0f);
                v = make_float2(dv * fmaf(xx.x, dv, ax), dv * fmaf(xx.y, dv, ay));
            }
            ubuf[i >> 7][i & 127] = v;
        }
        if (lane < 16) ubuf[lane][SEQ] = make_float2(0.f, 0.f);
    }

    // ---- constant A-frags: 8 tiles [gate g][half t1], hi/lo bf16 split ----
    short8 AiH[4][2], AiL[4][2], AhH[4][2], AhL[4][2];
    floatx4 biasC[4][2];
    #pragma unroll
    for (int g = 0; g < 4; ++g) {
        #pragma unroll
        for (int t1 = 0; t1 < 2; ++t1) {
            const int arow = g * 32 + 8 * (n >> 2) + 4 * t1 + (n & 3);
            const float* wi = w_ih + arow * HID + 8 * qq;
            const float* wh = w_hh + arow * HID + 8 * qq;
            #pragma unroll
            for (int j = 0; j < 8; ++j) {
                short h16, l16;
                fsplit(wi[j], h16, l16); AiH[g][t1][j] = h16; AiL[g][t1][j] = l16;
                fsplit(wh[j], h16, l16); AhH[g][t1][j] = h16; AhL[g][t1][j] = l16;
            }
            #pragma unroll
            for (int r = 0; r < 4; ++r) {
                const int brow = g * 32 + 8 * qq + 4 * t1 + r;
                biasC[g][t1][r] = b_ih[brow] + b_hh[brow];
            }
        }
    }

    // ---- GCN + FC consts for this lane's units u = 8qq + j ----
    float wg0[8], wg1[8], gbc[8], fcw[8];
    #pragma unroll
    for (int j = 0; j < 8; ++j) {
        const int u = 8 * qq + j;
        wg0[j] = gcn_W[u];
        wg1[j] = gcn_W[HID + u];
        gbc[j] = gcn_b[u];
        fcw[j] = fc_W[u];
    }

    float c[2][4], ho[2][4];
    #pragma unroll
    for (int t1 = 0; t1 < 2; ++t1)
        #pragma unroll
        for (int r = 0; r < 4; ++r) { c[t1][r] = 0.f; ho[t1][r] = 0.f; }

    short8 hh = (short8){0, 0, 0, 0, 0, 0, 0, 0};   // h(-1) = 0
    short8 hl = (short8){0, 0, 0, 0, 0, 0, 0, 0};
    short8 xh, xl;
    floatx4 aX[4][2];

    // ---- prologue: xg(0) frags + aX(0) = bias + Wi.xg(0) ----
    {
        float2 uu = ubuf[n][0];
        #pragma unroll
        for (int j = 0; j < 8; ++j) {
            float g = fmaxf(fmaf(uu.x, wg0[j], fmaf(uu.y, wg1[j], gbc[j])), 0.f);
            short h16, l16;
            fsplit(g, h16, l16);
            xh[j] = h16; xl[j] = l16;
        }
    }
    #pragma unroll
    for (int g = 0; g < 4; ++g)
        #pragma unroll
        for (int t1 = 0; t1 < 2; ++t1)
            aX[g][t1] = __builtin_amdgcn_mfma_f32_16x16x32_bf16(AiH[g][t1], xh, biasC[g][t1], 0, 0, 0);
    #pragma unroll
    for (int g = 0; g < 4; ++g)
        #pragma unroll
        for (int t1 = 0; t1 < 2; ++t1)
            aX[g][t1] = __builtin_amdgcn_mfma_f32_16x16x32_bf16(AiL[g][t1], xh, aX[g][t1], 0, 0, 0);
    #pragma unroll
    for (int g = 0; g < 4; ++g)
        #pragma unroll
        for (int t1 = 0; t1 < 2; ++t1)
            aX[g][t1] = __builtin_amdgcn_mfma_f32_16x16x32_bf16(AiH[g][t1], xl, aX[g][t1], 0, 0, 0);

    // ---- recurrence: pure registers + MFMA, zero barriers ----
    #pragma unroll 1
    for (int t = 0; t < SEQ; ++t) {
        // h-path: acc = aX(t) + Wh.h(t-1)   (3-term hi/lo, 8 independent tiles)
        floatx4 acc[4][2];
        #pragma unroll
        for (int g = 0; g < 4; ++g)
            #pragma unroll
            for (int t1 = 0; t1 < 2; ++t1)
                acc[g][t1] = __builtin_amdgcn_mfma_f32_16x16x32_bf16(AhH[g][t1], hh, aX[g][t1], 0, 0, 0);
        #pragma unroll
        for (int g = 0; g < 4; ++g)
            #pragma unroll
            for (int t1 = 0; t1 < 2; ++t1)
                acc[g][t1] = __builtin_amdgcn_mfma_f32_16x16x32_bf16(AhL[g][t1], hh, acc[g][t1], 0, 0, 0);
        #pragma unroll
        for (int g = 0; g < 4; ++g)
            #pragma unroll
            for (int t1 = 0; t1 < 2; ++t1)
                acc[g][t1] = __builtin_amdgcn_mfma_f32_16x16x32_bf16(AhH[g][t1], hl, acc[g][t1], 0, 0, 0);

        // xg(t+1) frags (ubuf-only dependency; overlaps h-MFMA latency)
        {
            float2 uu = ubuf[n][t + 1];
            #pragma unroll
            for (int j = 0; j < 8; ++j) {
                float g = fmaxf(fmaf(uu.x, wg0[j], fmaf(uu.y, wg1[j], gbc[j])), 0.f);
                short h16, l16;
                fsplit(g, h16, l16);
                xh[j] = h16; xl[j] = l16;
            }
        }
        // aX(t+1) = bias + Wi.xg(t+1)  (consumes aX(t) slots after h-path read them)
        #pragma unroll
        for (int g = 0; g < 4; ++g)
            #pragma unroll
            for (int t1 = 0; t1 < 2; ++t1)
                aX[g][t1] = __builtin_amdgcn_mfma_f32_16x16x32_bf16(AiH[g][t1], xh, biasC[g][t1], 0, 0, 0);
        #pragma unroll
        for (int g = 0; g < 4; ++g)
            #pragma unroll
            for (int t1 = 0; t1 < 2; ++t1)
                aX[g][t1] = __builtin_amdgcn_mfma_f32_16x16x32_bf16(AiL[g][t1], xh, aX[g][t1], 0, 0, 0);
        #pragma unroll
        for (int g = 0; g < 4; ++g)
            #pragma unroll
            for (int t1 = 0; t1 < 2; ++t1)
                aX[g][t1] = __builtin_amdgcn_mfma_f32_16x16x32_bf16(AiH[g][t1], xl, aX[g][t1], 0, 0, 0);

        // activations: lane-local (all 4 gates for units 8qq+4t1+r live here)
        #pragma unroll
        for (int t1 = 0; t1 < 2; ++t1) {
            #pragma unroll
            for (int r = 0; r < 4; ++r) {
                const float ig = sigm_f(acc[0][t1][r]);
                const float fg = sigm_f(acc[1][t1][r]);
                const float gg = tanh_f(acc[2][t1][r]);
                const float og = sigm_f(acc[3][t1][r]);
                c[t1][r] = fmaf(fg, c[t1][r], ig * gg);
                const float hv = og * tanh_f(c[t1][r]);
                ho[t1][r] = hv;
                short h16, l16;
                fsplit(hv, h16, l16);
                hh[4 * t1 + r] = h16;   // B-frag elem j = 4*t1+r == unit 8qq+j
                hl[4 * t1 + r] = l16;
            }
        }
    }

    // ---- FC epilogue: own 8 units, then reduce across the 4 qq lane-groups ----
    float partial = 0.f;
    #pragma unroll
    for (int t1 = 0; t1 < 2; ++t1)
        #pragma unroll
        for (int r = 0; r < 4; ++r)
            partial = fmaf(ho[t1][r], fcw[4 * t1 + r], partial);
    partial += __shfl_xor(partial, 16);
    partial += __shfl_xor(partial, 32);
    if (lane < 16) {
        const int node = base + n;
        if (node < N) out[node] = partial + fc_b[0];
    }
}

extern "C" void kernel_launch(void* const* d_in, const int* in_sizes, int n_in,
                              void* d_out, int out_size, void* d_ws, size_t ws_size,
                              hipStream_t stream) {
    const float* x     = (const float*)d_in[0];
    const int*   idx   = (const int*)d_in[1];
    const float* gcn_W = (const float*)d_in[2];
    const float* gcn_b = (const float*)d_in[3];
    const float* w_ih  = (const float*)d_in[4];
    const float* w_hh  = (const float*)d_in[5];
    const float* b_ih  = (const float*)d_in[6];
    const float* b_hh  = (const float*)d_in[7];
    const float* fc_W  = (const float*)d_in[8];
    const float* fc_b  = (const float*)d_in[9];

    const int num_nodes = in_sizes[0] / (SEQ * 2);
    const int ntot = num_nodes * SEQ;
    const int E = in_sizes[1] / 2;

    // workspace: deg[ntot i32] | aggP[ntot u64]  (3 planes of 4B)
    int* deg = (int*)d_ws;
    unsigned long long* aggP = (unsigned long long*)((char*)d_ws + (size_t)ntot * 4);

    hipMemsetAsync(d_ws, 0, (size_t)ntot * 12, stream);

    const int eb = (E + 1023) / 1024;  // 4 edges/thread, 256 threads/block
    count_kernel<<<eb, 256, 0, stream>>>(idx, E, deg);
    scatter_pk_kernel<<<eb, 256, 0, stream>>>(idx, E, (const float2*)x, deg, aggP);
    lstm_sw_kernel<<<(num_nodes + 15) / 16, 64, 0, stream>>>(
        (const float2*)x, aggP, deg, num_nodes,
        gcn_W, gcn_b, w_ih, w_hh, b_ih, b_hh, fc_W, fc_b,
        (float*)d_out);
}

// Round 7
// 484.275 us; speedup vs baseline: 1.1198x; 1.1198x over previous
//
#include <hip/hip_runtime.h>

#define SEQ 128
#define HID 32
#define TPB 256   // 4 waves, 16 nodes per block, gate-split across waves
#define XS 56     // LDS row stride in shorts: 112B = 7*16B (16B-aligned b128 rows)

typedef __attribute__((ext_vector_type(8))) short short8;   // 8 bf16 = 4 VGPR
typedef __attribute__((ext_vector_type(4))) float floatx4;  // MFMA acc

// ---------------- GCN prep (identical to round-5 verified version) ----------------

__global__ void count_kernel(const int* __restrict__ idx, int E, int* __restrict__ cnt) {
    int e = (blockIdx.x * blockDim.x + threadIdx.x) * 4;
    if (((E & 3) == 0) && e + 3 < E) {
        int4 d = *(const int4*)(idx + E + e);   // 16B aligned: E%4==0, e%4==0
        atomicAdd(&cnt[d.x], 1);
        atomicAdd(&cnt[d.y], 1);
        atomicAdd(&cnt[d.z], 1);
        atomicAdd(&cnt[d.w], 1);
    } else {
        int lim = min(e + 4, E);
        for (int k = e; k < lim; ++k) atomicAdd(&cnt[idx[E + k]], 1);
    }
}

// Fixed-point pack: q = rn(v * 2^21), biased +2^26 per 32b field -> every added term
// positive and < 2^26.2, no cross-field carry up to ~56 adds. ONE u64 atomic per
// edge; dinv[src] computed inline from the deg gather (scatter is atomic-rate-bound).
__device__ __forceinline__ unsigned long long pk2(float xx, float yy, float dv) {
    int qx = __float2int_rn(xx * dv * 2097152.0f);
    int qy = __float2int_rn(yy * dv * 2097152.0f);
    return ((unsigned long long)(unsigned)(qx + (1 << 26)) << 32) |
           (unsigned)(qy + (1 << 26));
}

__global__ void scatter_pk_kernel(const int* __restrict__ idx, int E,
                                  const float2* __restrict__ x2,
                                  const int* __restrict__ deg,
                                  unsigned long long* __restrict__ aggP) {
    int e = (blockIdx.x * blockDim.x + threadIdx.x) * 4;
    if (((E & 3) == 0) && e + 3 < E) {
        int4 s = *(const int4*)(idx + e);
        int4 d = *(const int4*)(idx + E + e);
        float2 v0 = x2[s.x];
        float2 v1 = x2[s.y];
        float2 v2 = x2[s.z];
        float2 v3 = x2[s.w];
        float dv0 = rsqrtf((float)deg[s.x] + 1.0f);
        float dv1 = rsqrtf((float)deg[s.y] + 1.0f);
        float dv2 = rsqrtf((float)deg[s.z] + 1.0f);
        float dv3 = rsqrtf((float)deg[s.w] + 1.0f);
        atomicAdd(&aggP[d.x], pk2(v0.x, v0.y, dv0));
        atomicAdd(&aggP[d.y], pk2(v1.x, v1.y, dv1));
        atomicAdd(&aggP[d.z], pk2(v2.x, v2.y, dv2));
        atomicAdd(&aggP[d.w], pk2(v3.x, v3.y, dv3));
    } else {
        int lim = min(e + 4, E);
        for (int k = e; k < lim; ++k) {
            int s = idx[k];
            int d = idx[E + k];
            float2 v = x2[s];
            float dv = rsqrtf((float)deg[s] + 1.0f);
            atomicAdd(&aggP[d], pk2(v.x, v.y, dv));
        }
    }
}

// ---------------- MFMA LSTM: 4-wave GATE-SPLIT, 16 nodes/block ----------------
// Occupancy is the lever (r3 vs r6: 4240 vs 5270 cyc/step at ~1.2 waves/SIMD).
// Node-parallelism caps at 1250 waves, so we split the GATE dim: wave w owns
// gate w (both 16-unit tiles), 5000 waves total -> ~4.9/SIMD with 4 blocks/CU.
// Identity A-rows: C row m <-> W row m (derived from the HW-verified permuted
// mapping: lane(n,q) reg r of tile t1 = unit 16*t1+4*q+r). Per step:
//   A: read h b128 -> 6 h-MFMAs (C-in = aX, one step ahead) -> own-gate
//      sigma/tanh in C-layout -> write activated gates to pre[4][32][17]
//   BAR1
//   B: lane gathers i,f,g,o for its 2 units (ua=8w+2q -> all LDS <=2-way
//      bank aliasing = free), c/h update (4 trans), write h + xg(t+1) hi/lo
//   BAR2
//   C: read xg b128 -> 6 x-MFMAs -> aX(t+1)
// Single-buffered LDS, 2 barriers/step: reads of buffer X always complete
// before the barrier that precedes the next write of X (implicit lgkmcnt(0)
// at s_barrier). All LDS addresses loop-invariant.

__device__ __forceinline__ float sigm_f(float x) {
    return __builtin_amdgcn_rcpf(1.0f + __expf(-x));
}
__device__ __forceinline__ float tanh_f(float x) {
    return fmaf(__builtin_amdgcn_rcpf(1.0f + __expf(-2.0f * x)), 2.0f, -1.0f);
}
// truncation split: f = hi + lo (~2^-16 rel); 3-term MFMA keeps fp32-like precision
__device__ __forceinline__ void fsplit(float f, short& hi, short& lo) {
    unsigned u = __float_as_uint(f);
    hi = (short)(u >> 16);
    float r = f - __uint_as_float(u & 0xFFFF0000u);
    lo = (short)(__float_as_uint(r) >> 16);
}
__device__ __forceinline__ int pks(short a, short b) {
    return (int)(((unsigned)(unsigned short)b << 16) | (unsigned short)a);
}

__global__ __launch_bounds__(TPB, 4) void lstm_gs_kernel(
    const float2* __restrict__ x2,
    const unsigned long long* __restrict__ aggP, const int* __restrict__ deg,
    int N,
    const float* __restrict__ gcn_W, const float* __restrict__ gcn_b,
    const float* __restrict__ w_ih, const float* __restrict__ w_hh,
    const float* __restrict__ b_ih, const float* __restrict__ b_hh,
    const float* __restrict__ fc_W, const float* __restrict__ fc_b,
    float* __restrict__ out) {
    __shared__ float2 ubuf[16][SEQ + 1];              // 16.5 KB; col 128 = zero pad
    __shared__ float pre[4][32][17];                  // 8.7 KB activated gates [g][u][n]
    __shared__ __align__(16) short hhb[16][XS];       // h hi  [node][unit]
    __shared__ __align__(16) short hlb[16][XS];       // h lo
    __shared__ __align__(16) short xgb[16][XS];       // xg hi
    __shared__ __align__(16) short xlb[16][XS];       // xg lo
    __shared__ float fcp[4][16];

    const int tid = threadIdx.x;
    const int w = tid >> 6;        // wave id == gate id
    const int lane = tid & 63;
    const int n = lane & 15;       // node (and A-row index in frag loads)
    const int q = lane >> 4;       // k-slice / C-row-group
    const int base = blockIdx.x * 16;

    // ---- stage u[node][t] = dv*(agg + x*dv) into LDS (coalesced, 8 iters) ----
    {
        const float2* xb = x2 + (size_t)base * SEQ;
        const unsigned long long* apb = aggP + (size_t)base * SEQ;
        const int* dgb = deg + (size_t)base * SEQ;
        const int lim = min(16 * SEQ, (N - base) * SEQ);
        for (int i = tid; i < 16 * SEQ; i += TPB) {
            float2 v = make_float2(0.f, 0.f);
            if (i < lim) {
                int dg = dgb[i];
                float dv = rsqrtf((float)dg + 1.0f);
                float2 xx = xb[i];
                unsigned long long pk = apb[i];
                unsigned bias = (unsigned)dg * 67108864u;  // deg * 2^26
                float ax = (float)((int)((unsigned)(pk >> 32) - bias)) * (1.0f / 2097152.0f);
                float ay = (float)((int)((unsigned)pk - bias)) * (1.0f / 2097152.0f);
                v = make_float2(dv * fmaf(xx.x, dv, ax), dv * fmaf(xx.y, dv, ay));
            }
            ubuf[i >> 7][i & 127] = v;
        }
        if (tid < 16) ubuf[tid][SEQ] = make_float2(0.f, 0.f);
    }

    // ---- A-frags for gate w, tiles t1 (identity rows), hi/lo bf16 split ----
    short8 AiH[2], AiL[2], AhH[2], AhL[2];
    floatx4 biasC[2];
    #pragma unroll
    for (int t1 = 0; t1 < 2; ++t1) {
        const int arow = w * 32 + 16 * t1 + n;      // A-frag row index = lane&15
        const float* wi = w_ih + arow * HID + 8 * q;
        const float* wh = w_hh + arow * HID + 8 * q;
        #pragma unroll
        for (int j = 0; j < 8; ++j) {
            short h16, l16;
            fsplit(wi[j], h16, l16); AiH[t1][j] = h16; AiL[t1][j] = l16;
            fsplit(wh[j], h16, l16); AhH[t1][j] = h16; AhL[t1][j] = l16;
        }
        #pragma unroll
        for (int r = 0; r < 4; ++r) {
            const int brow = w * 32 + 16 * t1 + 4 * q + r;  // C row = 4q+r
            biasC[t1][r] = b_ih[brow] + b_hh[brow];
        }
    }

    // ---- owned units for act/h/xg: ua, ua+1 (ua = 8w+2q -> conflict-free LDS) ----
    const int ua = 8 * w + 2 * q;
    const float wg0a = gcn_W[ua],       wg0b = gcn_W[ua + 1];
    const float wg1a = gcn_W[HID + ua], wg1b = gcn_W[HID + ua + 1];
    const float gbca = gcn_b[ua],       gbcb = gcn_b[ua + 1];
    const float fcwa = fc_W[ua],        fcwb = fc_W[ua + 1];

    float c0 = 0.f, c1 = 0.f, ho0 = 0.f, ho1 = 0.f;

    __syncthreads();   // ubuf staged

    // ---- prologue: h(-1)=0 and xg(0) ----
    *(int*)&hhb[n][ua] = 0;
    *(int*)&hlb[n][ua] = 0;
    {
        float2 uu = ubuf[n][0];
        float ga = fmaxf(fmaf(uu.x, wg0a, fmaf(uu.y, wg1a, gbca)), 0.f);
        float gb = fmaxf(fmaf(uu.x, wg0b, fmaf(uu.y, wg1b, gbcb)), 0.f);
        short gah, gal, gbh, gbl;
        fsplit(ga, gah, gal); fsplit(gb, gbh, gbl);
        *(int*)&xgb[n][ua] = pks(gah, gbh);
        *(int*)&xlb[n][ua] = pks(gal, gbl);
    }
    __syncthreads();

    // ---- aX(0) = bias + Wi.xg(0) ----
    floatx4 aX[2];
    {
        const short8 xh = *(const short8*)&xgb[n][8 * q];
        const short8 xl = *(const short8*)&xlb[n][8 * q];
        __builtin_amdgcn_s_setprio(1);
        #pragma unroll
        for (int t1 = 0; t1 < 2; ++t1)
            aX[t1] = __builtin_amdgcn_mfma_f32_16x16x32_bf16(AiH[t1], xh, biasC[t1], 0, 0, 0);
        #pragma unroll
        for (int t1 = 0; t1 < 2; ++t1)
            aX[t1] = __builtin_amdgcn_mfma_f32_16x16x32_bf16(AiL[t1], xh, aX[t1], 0, 0, 0);
        #pragma unroll
        for (int t1 = 0; t1 < 2; ++t1)
            aX[t1] = __builtin_amdgcn_mfma_f32_16x16x32_bf16(AiH[t1], xl, aX[t1], 0, 0, 0);
        __builtin_amdgcn_s_setprio(0);
    }

    #pragma unroll 1
    for (int t = 0; t < SEQ; ++t) {
        // ---- phase A: h-path MFMAs + own-gate nonlinearity + pre write ----
        {
            const short8 hh = *(const short8*)&hhb[n][8 * q];
            const short8 hl = *(const short8*)&hlb[n][8 * q];
            floatx4 acc[2];
            __builtin_amdgcn_s_setprio(1);
            #pragma unroll
            for (int t1 = 0; t1 < 2; ++t1)
                acc[t1] = __builtin_amdgcn_mfma_f32_16x16x32_bf16(AhH[t1], hh, aX[t1], 0, 0, 0);
            #pragma unroll
            for (int t1 = 0; t1 < 2; ++t1)
                acc[t1] = __builtin_amdgcn_mfma_f32_16x16x32_bf16(AhL[t1], hh, acc[t1], 0, 0, 0);
            #pragma unroll
            for (int t1 = 0; t1 < 2; ++t1)
                acc[t1] = __builtin_amdgcn_mfma_f32_16x16x32_bf16(AhH[t1], hl, acc[t1], 0, 0, 0);
            __builtin_amdgcn_s_setprio(0);
            float av[8];
            #pragma unroll
            for (int t1 = 0; t1 < 2; ++t1)
                #pragma unroll
                for (int r = 0; r < 4; ++r) av[4 * t1 + r] = acc[t1][r];
            if (w == 2) {   // gate g~ -> tanh; wave-uniform branch
                #pragma unroll
                for (int k = 0; k < 8; ++k) av[k] = tanh_f(av[k]);
            } else {        // gates i,f,o -> sigmoid
                #pragma unroll
                for (int k = 0; k < 8; ++k) av[k] = sigm_f(av[k]);
            }
            #pragma unroll
            for (int t1 = 0; t1 < 2; ++t1)
                #pragma unroll
                for (int r = 0; r < 4; ++r)
                    pre[w][16 * t1 + 4 * q + r][n] = av[4 * t1 + r];
        }
        __syncthreads();   // BAR1: pre complete

        // ---- phase B: gather 4 gates for 2 owned units; c/h update; write h, xg ----
        {
            const float i0 = pre[0][ua][n],     f0 = pre[1][ua][n];
            const float g0 = pre[2][ua][n],     o0 = pre[3][ua][n];
            const float i1 = pre[0][ua + 1][n], f1 = pre[1][ua + 1][n];
            const float g1 = pre[2][ua + 1][n], o1 = pre[3][ua + 1][n];
            c0 = fmaf(f0, c0, i0 * g0);
            c1 = fmaf(f1, c1, i1 * g1);
            const float h0 = o0 * tanh_f(c0);
            const float h1 = o1 * tanh_f(c1);
            ho0 = h0; ho1 = h1;
            short h0h, h0l, h1h, h1l;
            fsplit(h0, h0h, h0l); fsplit(h1, h1h, h1l);
            *(int*)&hhb[n][ua] = pks(h0h, h1h);
            *(int*)&hlb[n][ua] = pks(h0l, h1l);
            // xg(t+1): t=127 reads zero pad col; result never consumed
            float2 uu = ubuf[n][t + 1];
            float ga = fmaxf(fmaf(uu.x, wg0a, fmaf(uu.y, wg1a, gbca)), 0.f);
            float gb = fmaxf(fmaf(uu.x, wg0b, fmaf(uu.y, wg1b, gbcb)), 0.f);
            short gah, gal, gbh, gbl;
            fsplit(ga, gah, gal); fsplit(gb, gbh, gbl);
            *(int*)&xgb[n][ua] = pks(gah, gbh);
            *(int*)&xlb[n][ua] = pks(gal, gbl);
        }
        __syncthreads();   // BAR2: h + xg complete

        // ---- phase C: aX(t+1) = bias + Wi.xg(t+1) ----
        {
            const short8 xh = *(const short8*)&xgb[n][8 * q];
            const short8 xl = *(const short8*)&xlb[n][8 * q];
            __builtin_amdgcn_s_setprio(1);
            #pragma unroll
            for (int t1 = 0; t1 < 2; ++t1)
                aX[t1] = __builtin_amdgcn_mfma_f32_16x16x32_bf16(AiH[t1], xh, biasC[t1], 0, 0, 0);
            #pragma unroll
            for (int t1 = 0; t1 < 2; ++t1)
                aX[t1] = __builtin_amdgcn_mfma_f32_16x16x32_bf16(AiL[t1], xh, aX[t1], 0, 0, 0);
            #pragma unroll
            for (int t1 = 0; t1 < 2; ++t1)
                aX[t1] = __builtin_amdgcn_mfma_f32_16x16x32_bf16(AiH[t1], xl, aX[t1], 0, 0, 0);
            __builtin_amdgcn_s_setprio(0);
        }
    }

    // ---- FC epilogue: 2 owned units, reduce over q (shfl) then waves (LDS) ----
    float partial = fmaf(ho0, fcwa, ho1 * fcwb);
    partial += __shfl_xor(partial, 16);
    partial += __shfl_xor(partial, 32);
    if (lane < 16) fcp[w][lane] = partial;
    __syncthreads();
    if (w == 0 && lane < 16) {
        const int node = base + lane;
        if (node < N)
            out[node] = fcp[0][lane] + fcp[1][lane] + fcp[2][lane] + fcp[3][lane] + fc_b[0];
    }
}

extern "C" void kernel_launch(void* const* d_in, const int* in_sizes, int n_in,
                              void* d_out, int out_size, void* d_ws, size_t ws_size,
                              hipStream_t stream) {
    const float* x     = (const float*)d_in[0];
    const int*   idx   = (const int*)d_in[1];
    const float* gcn_W = (const float*)d_in[2];
    const float* gcn_b = (const float*)d_in[3];
    const float* w_ih  = (const float*)d_in[4];
    const float* w_hh  = (const float*)d_in[5];
    const float* b_ih  = (const float*)d_in[6];
    const float* b_hh  = (const float*)d_in[7];
    const float* fc_W  = (const float*)d_in[8];
    const float* fc_b  = (const float*)d_in[9];

    const int num_nodes = in_sizes[0] / (SEQ * 2);
    const int ntot = num_nodes * SEQ;
    const int E = in_sizes[1] / 2;

    // workspace: deg[ntot i32] | aggP[ntot u64]  (3 planes of 4B)
    int* deg = (int*)d_ws;
    unsigned long long* aggP = (unsigned long long*)((char*)d_ws + (size_t)ntot * 4);

    hipMemsetAsync(d_ws, 0, (size_t)ntot * 12, stream);

    const int eb = (E + 1023) / 1024;  // 4 edges/thread, 256 threads/block
    count_kernel<<<eb, 256, 0, stream>>>(idx, E, deg);
    scatter_pk_kernel<<<eb, 256, 0, stream>>>(idx, E, (const float2*)x, deg, aggP);
    lstm_gs_kernel<<<(num_nodes + 15) / 16, TPB, 0, stream>>>(
        (const float2*)x, aggP, deg, num_nodes,
        gcn_W, gcn_b, w_ih, w_hh, b_ih, b_hh, fc_W, fc_b,
        (float*)d_out);
}